// Round 9
// baseline (29.030 us; speedup 1.0000x reference)
//
#include <hip/hip_runtime.h>

#define NATOMS 25000
#define NSP 64
#define NRANGE 16
#define RSIZE ((NATOMS + NRANGE - 1) / NRANGE)   // 1563 atoms per range
#define SCAN_IT ((RSIZE + 255) / 256)            // 7
#define LCAP ((RSIZE + 31) & ~31)                // 1568

typedef short bf16x8 __attribute__((ext_vector_type(8)));   // 8 bf16 = 4 VGPRs
typedef float f32x4  __attribute__((ext_vector_type(4)));
typedef unsigned short u16;

// f32 -> bf16 round-to-nearest-even
__device__ __forceinline__ u16 f2bf(float f) {
  unsigned u = __float_as_uint(f);
  u += 0x7fffu + ((u >> 16) & 1u);
  return (u16)(u >> 16);
}

// ---- prep: W f32 -> bf16, plain [s][o][i]. 2 MB result: L2-resident everywhere ----
__global__ __launch_bounds__(256)
void conv_w(const float* __restrict__ w, u16* __restrict__ wbf) {
  int g = blockIdx.x * 256 + threadIdx.x;
  const float4* p = (const float4*)w + (size_t)g * 2;
  float4 v0 = p[0], v1 = p[1];
  union { u16 h[8]; bf16x8 v; } uu;
  uu.h[0] = f2bf(v0.x); uu.h[1] = f2bf(v0.y);
  uu.h[2] = f2bf(v0.z); uu.h[3] = f2bf(v0.w);
  uu.h[4] = f2bf(v1.x); uu.h[5] = f2bf(v1.y);
  uu.h[6] = f2bf(v1.z); uu.h[7] = f2bf(v1.w);
  ((bf16x8*)wbf)[g] = uu.v;
}

// ---- main: 1024 blocks = 64 species x 16 ranges. NO W staging: B-frags come
// straight from global bf16 W (2 MB total -> L2-hit after warmup). Block is
// just scan -> gather -> MFMA -> store; LDS = 3 KB; 4 blocks/CU TLP. ----
__global__ __launch_bounds__(256)
void zcl_main(const float* __restrict__ feat, const int* __restrict__ sp,
              const u16* __restrict__ wbf, const float* __restrict__ bias,
              float* __restrict__ out)
{
  __shared__ u16 list[LCAP];   // 3.1 KiB
  __shared__ int nM;

  const int tid = threadIdx.x, bid = blockIdx.x;
  const int s = bid & 63;      // consecutive bids = same range, different species
  const int r = bid >> 6;      //   -> the 64 blocks covering one feat window co-run
  const int lo = r * RSIZE;
  const int hi = (lo + RSIZE < NATOMS) ? (lo + RSIZE) : NATOMS;

  const int wv = tid >> 6, lane = tid & 63;
  const int l16 = lane & 15, kq = lane >> 4;

  // 1) sp preload (the only block-wide dependency)
  int spv[SCAN_IT];
  #pragma unroll
  for (int i = 0; i < SCAN_IT; ++i) {
    int a = lo + i * 256 + tid;
    spv[i] = (a < hi) ? sp[a] : -1;
  }

  // bias hoist (L2-hot; consumed only at stores)
  float bvb[8];
  #pragma unroll
  for (int nf = 0; nf < 8; ++nf) bvb[nf] = bias[s * 128 + l16 + 16 * nf];

  if (tid == 0) nM = 0;
  __syncthreads();

  // 2) block-shared compact scan
  #pragma unroll
  for (int i = 0; i < SCAN_IT; ++i) {
    bool m = (spv[i] == s);
    unsigned long long mk = __ballot(m);
    int base = 0;
    if (lane == 0) base = atomicAdd(&nM, (int)__popcll(mk));
    base = __shfl(base, 0);
    if (m) list[base + __popcll(mk & ((1ull << lane) - 1ull))] =
             (u16)(lo + i * 256 + tid);
  }
  __syncthreads();

  const int nMatch = nM;
  const int nt = (nMatch + 15) >> 4;
  const u16* wsrc = wbf + (size_t)s * 16384;

  // 3) tiles round-robin across waves (typically 2 tiles/block at this grid)
  for (int t = wv; t < nt; t += 4) {
    // feat gather: lane (l16,kq) = atom row l16, k-chunk kq (L2-line friendly:
    // 4 lanes x 16B at stride 32 within each row segment)
    int li = t * 16 + l16;
    int atomA = list[li < nMatch ? li : 0];
    const float4* xg = (const float4*)(feat + (size_t)atomA * 128);
    float4 pf[8];
    #pragma unroll
    for (int ks = 0; ks < 4; ++ks) {
      pf[2 * ks]     = xg[ks * 8 + kq * 2];
      pf[2 * ks + 1] = xg[ks * 8 + kq * 2 + 1];
    }

    bf16x8 av[4];
    #pragma unroll
    for (int ks = 0; ks < 4; ++ks) {
      union { u16 h[8]; bf16x8 v; } uu;
      uu.h[0] = f2bf(pf[2 * ks].x);     uu.h[1] = f2bf(pf[2 * ks].y);
      uu.h[2] = f2bf(pf[2 * ks].z);     uu.h[3] = f2bf(pf[2 * ks].w);
      uu.h[4] = f2bf(pf[2 * ks + 1].x); uu.h[5] = f2bf(pf[2 * ks + 1].y);
      uu.h[6] = f2bf(pf[2 * ks + 1].z); uu.h[7] = f2bf(pf[2 * ks + 1].w);
      av[ks] = uu.v;
    }

    // 16(M) x 128(N) x 128(K): 32 MFMA, B-frags straight from L2-resident W.
    // B addr: lane (l16,kq) reads W row (l16+16nf), k-bytes [ (ks*4+kq)*16, +16 )
    f32x4 acc[8];
    #pragma unroll
    for (int nf = 0; nf < 8; ++nf) acc[nf] = (f32x4){0.f, 0.f, 0.f, 0.f};
    #pragma unroll
    for (int ks = 0; ks < 4; ++ks) {
      #pragma unroll
      for (int nf = 0; nf < 8; ++nf) {
        bf16x8 b = *(const bf16x8*)&wsrc[(l16 + 16 * nf) * 128 + (ks * 4 + kq) * 8];
        acc[nf] = __builtin_amdgcn_mfma_f32_16x16x32_bf16(av[ks], b, acc[nf], 0, 0, 0);
      }
    }

    // store: D row = kq*4+q -> atom; col = l16 -> out channel l16+16*nf
    #pragma unroll
    for (int q = 0; q < 4; ++q) {
      int li2 = t * 16 + kq * 4 + q;
      if (li2 < nMatch) {
        int atom = list[li2];
        float* op = out + (size_t)atom * 128 + l16;
        #pragma unroll
        for (int nf = 0; nf < 8; ++nf) op[16 * nf] = acc[nf][q] + bvb[nf];
      }
    }
  }
}

extern "C" void kernel_launch(void* const* d_in, const int* in_sizes, int n_in,
                              void* d_out, int out_size, void* d_ws, size_t ws_size,
                              hipStream_t stream) {
  const float* feat   = (const float*)d_in[0];
  const int*   sp     = (const int*)d_in[1];
  const float* weight = (const float*)d_in[2];
  const float* bias   = (const float*)d_in[3];
  float*       out    = (float*)d_out;
  u16*         wbf    = (u16*)d_ws;    // 2 MiB scratch

  conv_w<<<512, 256, 0, stream>>>(weight, wbf);
  zcl_main<<<NSP * NRANGE, 256, 0, stream>>>(feat, sp, wbf, bias, out);
}

// Round 11
// 15.695 us; speedup vs baseline: 1.8496x; 1.8496x over previous
//
#include <hip/hip_runtime.h>

#define NATOMS 25000
#define NSP 64
#define NRANGE 16
#define RSIZE ((NATOMS + NRANGE - 1) / NRANGE)   // 1563 atoms per range
#define NWAVE 4
#define WSUB ((RSIZE + NWAVE - 1) / NWAVE)       // 391 atoms per wave
#define WIT ((WSUB + 63) / 64)                   // 7 scan iters per wave
#define LCAP (WIT * 64)                          // 448

typedef short bf16x8 __attribute__((ext_vector_type(8)));   // 8 bf16 = 4 VGPRs
typedef float f32x4  __attribute__((ext_vector_type(4)));
typedef unsigned short u16;

// f32 -> bf16 round-to-nearest-even
__device__ __forceinline__ u16 f2bf(float f) {
  unsigned u = __float_as_uint(f);
  u += 0x7fffu + ((u >> 16) & 1u);
  return (u16)(u >> 16);
}

// Single kernel, 1024 blocks = 64 species x 16 ranges, 256 thr.
// Register-frugal: W staged f32->bf16 in TWO 32-VGPR rounds so peak VGPR
// ~110 -> 4 blocks/CU (LDS 35.6KB*4 = 142 <= 160), 16 waves/CU TLP.
// NO __launch_bounds__ min-occupancy arg (R5/R6 lesson: it forces spills).
__global__ __launch_bounds__(256)
void zcl_kernel(const float* __restrict__ feat,
                const int*   __restrict__ sp,
                const float* __restrict__ weight,
                const float* __restrict__ bias,
                float*       __restrict__ out)
{
  // W[o][i] bf16, rows of 128; 16B chunks XOR-swizzled by (row&7) so B-frag
  // ds_read_b128 (lanes differ in row, fixed k-chunk) spreads all 32 banks.
  __shared__ u16 Ws[128 * 128];        // 32 KiB
  __shared__ u16 wlist[NWAVE][LCAP];   // 3.5 KiB wave-private lists

  const int tid = threadIdx.x, bid = blockIdx.x;
  // XCD pin: species s -> XCD s%8; W f32 working set/XCD = 8 sp * 64KB = 512KB
  // (L2-resident re-reads across that XCD's 16 range-blocks).
  const int s = (bid & 7) + 8 * ((bid >> 3) & 7);
  const int r = bid >> 6;
  const int lo = r * RSIZE;
  const int hi = (lo + RSIZE < NATOMS) ? (lo + RSIZE) : NATOMS;

  const int wv = tid >> 6, lane = tid & 63;
  const int l16 = lane & 15, kq = lane >> 4;
  const int wlo = lo + wv * WSUB;
  const int whi = (wlo + WSUB < hi) ? (wlo + WSUB) : hi;

  // 1) sp preload FIRST (oldest in vmcnt FIFO; scan's wait leaves W in flight)
  int spv[WIT];
  #pragma unroll
  for (int i = 0; i < WIT; ++i) {
    int a = wlo + i * 64 + lane;
    spv[i] = (a < whi) ? sp[a] : -1;
  }

  // 2) W staging round A: chunks 0..1023 (8 float4 = 32 VGPR)
  const float4* wg = (const float4*)(weight + (size_t)s * (128 * 128));
  float4 wA[8];
  #pragma unroll
  for (int q = 0; q < 4; ++q) {
    int m = q * 256 + tid;               // chunk: row=m>>4, 8-elem group c=m&15
    int row = m >> 4, c = m & 15;
    wA[2 * q]     = wg[row * 32 + c * 2];
    wA[2 * q + 1] = wg[row * 32 + c * 2 + 1];
  }

  // 3) wave-private compact scan (no atomics, no barriers; waits sp only)
  int wcnt = 0;
  #pragma unroll
  for (int i = 0; i < WIT; ++i) {
    bool m = (spv[i] == s);
    unsigned long long mk = __ballot(m);
    if (m) wlist[wv][wcnt + __popcll(mk & ((1ull << lane) - 1ull))] =
             (u16)(wlo + i * 64 + lane);
    wcnt += (int)__popcll(mk);
  }
  const int nt = (wcnt + 15) >> 4;

  // 4) convert round A -> Ws; round B load+convert (reuse the 32 VGPRs)
  #pragma unroll
  for (int q = 0; q < 4; ++q) {
    int m = q * 256 + tid;
    int row = m >> 4, c = m & 15;
    union { u16 h[8]; bf16x8 v; } uu;
    uu.h[0] = f2bf(wA[2 * q].x);     uu.h[1] = f2bf(wA[2 * q].y);
    uu.h[2] = f2bf(wA[2 * q].z);     uu.h[3] = f2bf(wA[2 * q].w);
    uu.h[4] = f2bf(wA[2 * q + 1].x); uu.h[5] = f2bf(wA[2 * q + 1].y);
    uu.h[6] = f2bf(wA[2 * q + 1].z); uu.h[7] = f2bf(wA[2 * q + 1].w);
    *(bf16x8*)&Ws[row * 128 + ((c ^ (row & 7)) << 3)] = uu.v;
  }
  #pragma unroll
  for (int q = 0; q < 4; ++q) {          // round B: chunks 1024..2047
    int m = 1024 + q * 256 + tid;
    int row = m >> 4, c = m & 15;
    wA[2 * q]     = wg[row * 32 + c * 2];
    wA[2 * q + 1] = wg[row * 32 + c * 2 + 1];
  }
  #pragma unroll
  for (int q = 0; q < 4; ++q) {
    int m = 1024 + q * 256 + tid;
    int row = m >> 4, c = m & 15;
    union { u16 h[8]; bf16x8 v; } uu;
    uu.h[0] = f2bf(wA[2 * q].x);     uu.h[1] = f2bf(wA[2 * q].y);
    uu.h[2] = f2bf(wA[2 * q].z);     uu.h[3] = f2bf(wA[2 * q].w);
    uu.h[4] = f2bf(wA[2 * q + 1].x); uu.h[5] = f2bf(wA[2 * q + 1].y);
    uu.h[6] = f2bf(wA[2 * q + 1].z); uu.h[7] = f2bf(wA[2 * q + 1].w);
    *(bf16x8*)&Ws[row * 128 + ((c ^ (row & 7)) << 3)] = uu.v;
  }

  __syncthreads();   // Ws visible; wlist already wave-local

  // bias (L2-hot; consumed only at stores)
  float bvb[8];
  #pragma unroll
  for (int nf = 0; nf < 8; ++nf) bvb[nf] = bias[s * 128 + l16 + 16 * nf];

  // 5) wave-independent tile loop (16 atoms x 128 outs x K=128)
  if (nt == 0) return;
  float4 pf[8];
  {
    int atomA = wlist[wv][l16 < wcnt ? l16 : 0];
    const float4* xg = (const float4*)(feat + (size_t)atomA * 128);
    #pragma unroll
    for (int ks = 0; ks < 4; ++ks) {
      pf[2 * ks]     = xg[ks * 8 + kq * 2];
      pf[2 * ks + 1] = xg[ks * 8 + kq * 2 + 1];
    }
  }

  for (int t = 0; t < nt; ++t) {
    bf16x8 av[4];
    #pragma unroll
    for (int ks = 0; ks < 4; ++ks) {
      union { u16 h[8]; bf16x8 v; } uu;
      uu.h[0] = f2bf(pf[2 * ks].x);     uu.h[1] = f2bf(pf[2 * ks].y);
      uu.h[2] = f2bf(pf[2 * ks].z);     uu.h[3] = f2bf(pf[2 * ks].w);
      uu.h[4] = f2bf(pf[2 * ks + 1].x); uu.h[5] = f2bf(pf[2 * ks + 1].y);
      uu.h[6] = f2bf(pf[2 * ks + 1].z); uu.h[7] = f2bf(pf[2 * ks + 1].w);
      av[ks] = uu.v;
    }

    if (t + 1 < nt) {   // prefetch next tile (overlaps MFMA + stores)
      int li = (t + 1) * 16 + l16;
      int atomA = wlist[wv][li < wcnt ? li : 0];
      const float4* xg = (const float4*)(feat + (size_t)atomA * 128);
      #pragma unroll
      for (int ks = 0; ks < 4; ++ks) {
        pf[2 * ks]     = xg[ks * 8 + kq * 2];
        pf[2 * ks + 1] = xg[ks * 8 + kq * 2 + 1];
      }
    }

    f32x4 acc[8];
    #pragma unroll
    for (int nf = 0; nf < 8; ++nf) acc[nf] = (f32x4){0.f, 0.f, 0.f, 0.f};
    #pragma unroll
    for (int ks = 0; ks < 4; ++ks) {
      int chunk = ((ks * 4 + kq) ^ (l16 & 7)) << 3;   // row&7 == l16&7 for all nf
      #pragma unroll
      for (int nf = 0; nf < 8; ++nf) {
        bf16x8 b = *(const bf16x8*)&Ws[(l16 + 16 * nf) * 128 + chunk];
        acc[nf] = __builtin_amdgcn_mfma_f32_16x16x32_bf16(av[ks], b, acc[nf], 0, 0, 0);
      }
    }

    // store: D row = kq*4+q -> atom; col = l16 -> out channel l16+16*nf
    #pragma unroll
    for (int q = 0; q < 4; ++q) {
      int li2 = t * 16 + kq * 4 + q;
      if (li2 < wcnt) {
        int atom = wlist[wv][li2];
        float* op = out + (size_t)atom * 128 + l16;
        #pragma unroll
        for (int nf = 0; nf < 8; ++nf) op[16 * nf] = acc[nf][q] + bvb[nf];
      }
    }
  }
}

extern "C" void kernel_launch(void* const* d_in, const int* in_sizes, int n_in,
                              void* d_out, int out_size, void* d_ws, size_t ws_size,
                              hipStream_t stream) {
  const float* feat   = (const float*)d_in[0];
  const int*   sp     = (const int*)d_in[1];
  const float* weight = (const float*)d_in[2];
  const float* bias   = (const float*)d_in[3];
  float*       out    = (float*)d_out;
  zcl_kernel<<<NSP * NRANGE, 256, 0, stream>>>(feat, sp, weight, bias, out);
}